// Round 11
// baseline (295.226 us; speedup 1.0000x reference)
//
#include <hip/hip_runtime.h>

#define B_   16
#define T_   512
#define C_   1024
#define D_   4096
#define K_   128
#define WIN_ 8
#define NW_  (T_ / WIN_)   // 64
#define M_   (B_ * T_)     // 8192

typedef __attribute__((ext_vector_type(8))) short bf16x8_t;
typedef __attribute__((ext_vector_type(4))) float f32x4_t;

__device__ __forceinline__ void gload16(const void* g, void* l) {
    __builtin_amdgcn_global_load_lds(
        (const __attribute__((address_space(1))) void*)g,
        (__attribute__((address_space(3))) void*)l, 16, 0, 0);
}

__device__ __forceinline__ unsigned short f2bf(float f) {
    unsigned u = __float_as_uint(f);
    unsigned r = (u + 0x7fffu + ((u >> 16) & 1u)) >> 16;
    return (unsigned short)r;
}

__device__ __forceinline__ unsigned f2key(float f) {
    unsigned u = __float_as_uint(f);
    return (u & 0x80000000u) ? ~u : (u | 0x80000000u);
}
__device__ __forceinline__ float key2f(unsigned k) {
    unsigned u = (k & 0x80000000u) ? (k & 0x7fffffffu) : ~k;
    return __uint_as_float(u);
}

// ---------------------------------------------------------------------------
// K0 (fused): wencbf = bf16(W_enc)  AND  benc2[d] = b_enc[d] - W_enc[d,:].b_dec
// ---------------------------------------------------------------------------
__global__ __launch_bounds__(256) void prep_cvt_wenc(
    const float* __restrict__ W_enc, const float* __restrict__ b_enc,
    const float* __restrict__ b_dec, unsigned short* __restrict__ wencbf,
    float* __restrict__ benc2)
{
    int d = blockIdx.x;
    int tid = threadIdx.x;
    float4 wv = ((const float4*)(W_enc + (size_t)d * C_))[tid];
    uint2 o;
    o.x = (unsigned)f2bf(wv.x) | ((unsigned)f2bf(wv.y) << 16);
    o.y = (unsigned)f2bf(wv.z) | ((unsigned)f2bf(wv.w) << 16);
    ((uint2*)(wencbf + (size_t)d * C_))[tid] = o;
    float4 bv = ((const float4*)b_dec)[tid];
    float s = wv.x * bv.x + wv.y * bv.y + wv.z * bv.z + wv.w * bv.w;
    __shared__ float red[256];
    red[tid] = s;
    __syncthreads();
    for (int off = 128; off > 0; off >>= 1) {
        if (tid < off) red[tid] += red[tid + off];
        __syncthreads();
    }
    if (tid == 0) benc2[d] = b_enc[d] - red[0];
}

// ---------------------------------------------------------------------------
// K1: fp32 -> bf16 (8 elems/thread) for x
// ---------------------------------------------------------------------------
__global__ void cvt_bf16(const float* __restrict__ in, unsigned short* __restrict__ out, int n8)
{
    int i = blockIdx.x * blockDim.x + threadIdx.x;
    if (i >= n8) return;
    const float4* p = (const float4*)(in + (size_t)i * 8);
    float4 a = p[0], b = p[1];
    uint4 o;
    o.x = (unsigned)f2bf(a.x) | ((unsigned)f2bf(a.y) << 16);
    o.y = (unsigned)f2bf(a.z) | ((unsigned)f2bf(a.w) << 16);
    o.z = (unsigned)f2bf(b.x) | ((unsigned)f2bf(b.y) << 16);
    o.w = (unsigned)f2bf(b.z) | ((unsigned)f2bf(b.w) << 16);
    ((uint4*)out)[i] = o;
}

// ---------------------------------------------------------------------------
// K2: transpose W_dec (C,D) -> WdT (D,C)
// ---------------------------------------------------------------------------
__global__ void transpose_wdec(const float* __restrict__ W, float* __restrict__ WT)
{
    __shared__ float tile[32][33];
    int d0 = blockIdx.x * 32;
    int c0 = blockIdx.y * 32;
    int tx = threadIdx.x, ty = threadIdx.y;  // (32,8)
    #pragma unroll
    for (int i = 0; i < 32; i += 8)
        tile[ty + i][tx] = W[(size_t)(c0 + ty + i) * D_ + d0 + tx];
    __syncthreads();
    #pragma unroll
    for (int i = 0; i < 32; i += 8)
        WT[(size_t)(d0 + ty + i) * C_ + c0 + tx] = tile[tx][ty + i];
}

// ---------------------------------------------------------------------------
// K3: bf16 MFMA GEMM — round-4/7/9/10 proven kernel, verbatim.
// ---------------------------------------------------------------------------
__global__ __launch_bounds__(256) void mfma_gemm_dense(
    const unsigned short* __restrict__ Abf,  // x bf16 (M_, C_)
    const unsigned short* __restrict__ Bbf,  // W_enc bf16 (D_, C_)
    const float* __restrict__ benc2,
    float* __restrict__ enc,                 // (M_, D_) dense activations
    float* __restrict__ wsums)               // (B_*NW_, D_)
{
    __shared__ unsigned short lA[128 * 32];
    __shared__ unsigned short lB[128 * 32];
    __shared__ float cst[4][16][68];         // wave-private C-stage (17 KB)
    int tid = threadIdx.x;
    int lane = tid & 63;
    int wv = tid >> 6;
    int wm = wv >> 1, wn = wv & 1;

    int lid = blockIdx.y * gridDim.x + blockIdx.x;
    int sw = (lid & 7) * 256 + (lid >> 3);
    int bn = sw & 31, bm = sw >> 5;

    f32x4_t acc[4][4];
    #pragma unroll
    for (int i = 0; i < 4; i++)
        #pragma unroll
        for (int j = 0; j < 4; j++) acc[i][j] = (f32x4_t){0.f, 0.f, 0.f, 0.f};

    const unsigned short* Ab = Abf + (size_t)bm * 128 * C_;
    const unsigned short* Bb = Bbf + (size_t)bn * 128 * C_;

    int m_s[2], u_s[2];
    #pragma unroll
    for (int q = 0; q < 2; q++) {
        int p = q * 256 + tid;
        int m = p >> 2, v = p & 3;
        m_s[q] = m;
        u_s[q] = v ^ ((m >> 1) & 3);
    }

    int r = lane & 15, g = lane >> 4;
    for (int k0 = 0; k0 < C_; k0 += 32) {
        __syncthreads();
        #pragma unroll
        for (int q = 0; q < 2; q++) {
            gload16(Ab + (size_t)m_s[q] * C_ + k0 + u_s[q] * 8,
                    &lA[(q * 256 + wv * 64) * 8]);
            gload16(Bb + (size_t)m_s[q] * C_ + k0 + u_s[q] * 8,
                    &lB[(q * 256 + wv * 64) * 8]);
        }
        __syncthreads();
        bf16x8_t af[4], bfr[4];
        #pragma unroll
        for (int mi = 0; mi < 4; mi++) {
            int m = wm * 64 + mi * 16 + r;
            int u = g ^ ((m >> 1) & 3);
            af[mi] = *(const bf16x8_t*)&lA[m * 32 + u * 8];
        }
        #pragma unroll
        for (int ni = 0; ni < 4; ni++) {
            int d = wn * 64 + ni * 16 + r;
            int u = g ^ ((d >> 1) & 3);
            bfr[ni] = *(const bf16x8_t*)&lB[d * 32 + u * 8];
        }
        #pragma unroll
        for (int mi = 0; mi < 4; mi++)
            #pragma unroll
            for (int ni = 0; ni < 4; ni++)
                acc[mi][ni] = __builtin_amdgcn_mfma_f32_16x16x32_bf16(
                    af[mi], bfr[ni], acc[mi][ni], 0, 0, 0);
    }

    int b = bm >> 2;
    int t_blk = (bm & 3) * 128;
    int dbase = bn * 128 + wn * 64;
    int mbase_w = bm * 128 + wm * 64;
    int wbase = b * NW_ + (t_blk >> 3) + wm * 8;

    float bias_r[4];
    #pragma unroll
    for (int ni = 0; ni < 4; ni++) bias_r[ni] = benc2[dbase + ni * 16 + r];

    float wsv[4][4];
    #pragma unroll
    for (int mi = 0; mi < 4; mi++) {
        #pragma unroll
        for (int ni = 0; ni < 4; ni++) {
            float s = 0.f;
            #pragma unroll
            for (int q = 0; q < 4; q++) {
                float v = acc[mi][ni][q] + bias_r[ni];
                v = v > 0.f ? v : 0.f;
                cst[wv][g * 4 + q][ni * 16 + r] = v;
                s += v;
            }
            float partner = __shfl_xor(s, 16);
            wsv[mi][ni] = s + partner;
        }
        #pragma unroll
        for (int ri = 0; ri < 4; ri++) {
            int row = ri * 4 + (lane >> 4);
            int c4 = (lane & 15) * 4;
            float4 vv = *(const float4*)&cst[wv][row][c4];
            *(float4*)(enc + (size_t)(mbase_w + mi * 16 + row) * D_ + dbase + c4) = vv;
        }
    }

    if ((g & 1) == 0) {
        #pragma unroll
        for (int mi = 0; mi < 4; mi++)
            #pragma unroll
            for (int ni = 0; ni < 4; ni++)
                cst[wv][mi * 2 + (g >> 1)][ni * 16 + r] = wsv[mi][ni];
    }
    #pragma unroll
    for (int it = 0; it < 2; it++) {
        int row = lane >> 3;
        int c4 = (lane & 7) * 4 + it * 32;
        float4 vv = *(const float4*)&cst[wv][row][c4];
        *(float4*)(wsums + (size_t)(wbase + row) * D_ + dbase + c4) = vv;
    }
}

// ---------------------------------------------------------------------------
// Selection helpers (NT-agnostic; hist is 256 bins)
// ---------------------------------------------------------------------------
__device__ __forceinline__ void find_bucket(
    const int* hist, int need, int shift, unsigned pref,
    unsigned* shp, int* shn, int tid)
{
    if (tid < 64) {
        int L = tid;
        int h0 = hist[L * 4], h1 = hist[L * 4 + 1];
        int h2 = hist[L * 4 + 2], h3 = hist[L * 4 + 3];
        int s3 = h3, s2 = h2 + s3, s1 = h1 + s2, s0 = h0 + s1;
        int T = s0, I = T;
        #pragma unroll
        for (int off = 1; off < 64; off <<= 1) {
            int t = __shfl_down(I, off);
            if (L + off < 64) I += t;
        }
        int H = I - T;   // suffix sum of buckets in higher lanes
        int S[5] = {H + s0, H + s1, H + s2, H + s3, H};
        #pragma unroll
        for (int j = 0; j < 4; j++) {
            if (S[j] >= need && S[j + 1] < need) {
                *shp = pref | ((unsigned)(L * 4 + j) << shift);
                *shn = need - S[j + 1];
            }
        }
    }
    __syncthreads();
}

__device__ __forceinline__ void radix_select(
    const unsigned* keys, int n, int need0, int npass, unsigned maxkey,
    int* hist, unsigned* shp, int* shn, int tid)
{
    if (tid == 0) { *shp = 0u; *shn = need0; }
    __syncthreads();
    for (int pass = 0; pass < npass; ++pass) {
        int shift = 24 - pass * 8;
        unsigned pref = *shp;
        int need = *shn;
        unsigned pmask = (pass == 0) ? 0u : (0xFFFFFFFFu << (shift + 8));
        if (tid < 256) hist[tid] = 0;
        __syncthreads();
        for (int i = tid; i < n; i += blockDim.x) {
            unsigned k = keys[i];
            if (k <= maxkey && (k & pmask) == pref)
                atomicAdd(&hist[(k >> shift) & 0xFF], 1);
        }
        __syncthreads();
        find_bucket(hist, need, shift, pref, shp, shn, tid);
    }
}

// exclusive prefix over up to 512 threads (wsum has 8 slots)
__device__ __forceinline__ int block_prefix_excl(int v, int* wsum, int tid)
{
    __syncthreads();                 // protect wsum reuse
    int lane = tid & 63, wv = tid >> 6;
    int x = v;
    #pragma unroll
    for (int off = 1; off < 64; off <<= 1) {
        int t = __shfl_up(x, off);
        if (lane >= off) x += t;
    }
    if (lane == 63) wsum[wv] = x;
    __syncthreads();
    int base = 0;
    #pragma unroll
    for (int w2 = 0; w2 < 7; w2++) if (w2 < wv) base += wsum[w2];
    return base + x - v;
}

// ---------------------------------------------------------------------------
// K4 (fused): round-10 logic, 512 threads (8 waves).  P2 serial depth 20->10,
// waves/CU 12->24.  Selection arithmetic bit-identical (per-candidate math
// and tie-break order unchanged; P4 redone for 8 keys/thread).
// ---------------------------------------------------------------------------
#define DELTA 0.15f
#define MAXCAND 320
#define FT_NT 512

__global__ __launch_bounds__(FT_NT) void fixup_topk(
    const float* __restrict__ wsums, const float* __restrict__ x,
    const float* __restrict__ W_enc, const float* __restrict__ benc2,
    unsigned* __restrict__ bmask, int* __restrict__ idxlist)
{
    int row = blockIdx.x;             // b*NW + w
    int b = row / NW_, w = row % NW_;
    int t0g = b * T_ + w * WIN_;
    __shared__ unsigned keys[D_];     // 16 KB (mixed approx/exact keys)
    __shared__ float xs[WIN_][C_];    // 32 KB (whist overlay during P1)
    __shared__ int hist[256];         // 1 KB (hbits overlay in P4)
    __shared__ int wsum[8];
    __shared__ unsigned sh_prefix;
    __shared__ int sh_need;
    __shared__ int cand[MAXCAND];
    __shared__ unsigned ckeys[MAXCAND];
    __shared__ int sh_ncand, sh_nhi;
    unsigned short* hbits = (unsigned short*)hist;   // 512 u16 = 1 KB, P4 only
    int* whist = (int*)xs;                           // [8][256], pass-0 only
    int tid = threadIdx.x;

    for (int i = tid; i < D_ / 4; i += FT_NT) {
        float4 v = ((const float4*)(wsums + (size_t)row * D_))[i];
        keys[i * 4 + 0] = f2key(v.x);
        keys[i * 4 + 1] = f2key(v.y);
        keys[i * 4 + 2] = f2key(v.z);
        keys[i * 4 + 3] = f2key(v.w);
    }
    for (int i = tid; i < 8 * 256; i += FT_NT) whist[i] = 0;
    if (tid == 0) { sh_ncand = 0; sh_nhi = 0; }
    __syncthreads();

    // ---- P1 pass 0: per-wave histograms (hot-bucket contention /8) ----
    {
        int* myh = whist + (tid >> 6) * 256;
        for (int i = tid; i < D_; i += FT_NT)
            atomicAdd(&myh[keys[i] >> 24], 1);
        __syncthreads();
        if (tid < 256) {
            int s = 0;
            #pragma unroll
            for (int wq = 0; wq < 8; wq++) s += whist[wq * 256 + tid];
            hist[tid] = s;
        }
        __syncthreads();
        find_bucket(hist, K_, 24, 0u, &sh_prefix, &sh_need, tid);
    }
    // ---- P1 passes 1..2 (24-bit prefix suffices) ----
    for (int pass = 1; pass < 3; ++pass) {
        int shift = 24 - pass * 8;
        unsigned pref = sh_prefix;
        int need = sh_need;
        unsigned pmask = 0xFFFFFFFFu << (shift + 8);
        if (tid < 256) hist[tid] = 0;
        __syncthreads();
        for (int i = tid; i < D_; i += FT_NT) {
            unsigned k = keys[i];
            if ((k & pmask) == pref)
                atomicAdd(&hist[(k >> shift) & 0xFF], 1);
        }
        __syncthreads();
        find_bucket(hist, need, shift, pref, &sh_prefix, &sh_need, tid);
    }
    float kthf = key2f(sh_prefix);
    unsigned TH_HI = f2key(kthf + DELTA);
    unsigned TH_LO = f2key(kthf - DELTA);

    // ---- load xs (whist region dead now) + collect candidates ----
    for (int i = tid; i < WIN_ * C_ / 4; i += FT_NT)
        ((float4*)xs)[i] = ((const float4*)(x + (size_t)t0g * C_))[i];
    {
        int myhi = 0;
        for (int i = tid; i < D_; i += FT_NT) {
            unsigned k = keys[i];
            if (k > TH_HI) myhi++;
            else if (k >= TH_LO) {
                int pos = atomicAdd(&sh_ncand, 1);
                if (pos < MAXCAND) cand[pos] = i;
            }
        }
        if (myhi) atomicAdd(&sh_nhi, myhi);
    }
    __syncthreads();
    int nc = sh_ncand < MAXCAND ? sh_ncand : MAXCAND;

    // ---- P2: exact fp32 recompute, 8 waves (serial depth halved) ----
    {
        int wvi = tid >> 6, ln = tid & 63;
        int c0 = ln * 4;
        for (int cb = wvi; cb < nc; cb += 8) {
            int d = cand[cb];
            const float* wrow = W_enc + (size_t)d * C_;
            float a[WIN_] = {0.f, 0.f, 0.f, 0.f, 0.f, 0.f, 0.f, 0.f};
            #pragma unroll
            for (int q = 0; q < 4; q++) {
                float4 wq = *(const float4*)(wrow + q * 256 + c0);
                #pragma unroll
                for (int j = 0; j < WIN_; j++) {
                    float4 xq = *(const float4*)(&xs[j][q * 256 + c0]);
                    a[j] = fmaf(wq.x, xq.x, a[j]);
                    a[j] = fmaf(wq.y, xq.y, a[j]);
                    a[j] = fmaf(wq.z, xq.z, a[j]);
                    a[j] = fmaf(wq.w, xq.w, a[j]);
                }
            }
            #pragma unroll
            for (int off = 1; off < 64; off <<= 1)
                #pragma unroll
                for (int j = 0; j < WIN_; j++) a[j] += __shfl_xor(a[j], off);
            if (ln == 0) {
                float bias = benc2[d], s = 0.f;
                #pragma unroll
                for (int j = 0; j < WIN_; j++) {
                    float v = a[j] + bias;
                    s += v > 0.f ? v : 0.f;
                }
                unsigned k1 = f2key(s);
                keys[d] = k1;
                ckeys[cb] = k1;
            }
        }
    }
    __syncthreads();

    // ---- P3: finish n_hi; exact select among candidates (or fallback) ----
    for (int i = tid; i < nc; i += FT_NT)
        if (ckeys[i] > TH_HI) atomicAdd(&sh_nhi, 1);
    __syncthreads();
    int need0 = K_ - sh_nhi;
    if (need0 > 0)
        radix_select(ckeys, nc, need0, 4, TH_HI, hist, &sh_prefix, &sh_need, tid);
    else
        radix_select(keys, D_, K_, 4, 0xFFFFFFFFu, hist, &sh_prefix, &sh_need, tid);
    unsigned kth = sh_prefix;
    int need_eq = sh_need;

    // ---- P4: emit bmask + ascending idxlist (8 keys/thread) ----
    int base8 = tid * 8;
    unsigned mybits = 0;
    int eqcnt = 0;
    #pragma unroll
    for (int j = 0; j < 8; ++j) {
        unsigned k = keys[base8 + j];
        if (k > kth) mybits |= (1u << j);
        else if (k == kth) eqcnt++;
    }
    int rr = block_prefix_excl(eqcnt, wsum, tid);
    #pragma unroll
    for (int j = 0; j < 8; ++j) {
        unsigned k = keys[base8 + j];
        if (k == kth) { if (rr < need_eq) mybits |= (1u << j); rr++; }
    }
    hbits[tid] = (unsigned short)mybits;     // hist dead from here on
    __syncthreads();
    if (tid < D_ / 32)
        bmask[(size_t)row * (D_ / 32) + tid] =
            (unsigned)hbits[4 * tid] | ((unsigned)hbits[4 * tid + 1] << 8) |
            ((unsigned)hbits[4 * tid + 2] << 16) | ((unsigned)hbits[4 * tid + 3] << 24);

    int pos = block_prefix_excl(__popc(mybits), wsum, tid);
    #pragma unroll
    for (int j = 0; j < 8; ++j) {
        if (mybits & (1u << j)) idxlist[(size_t)row * K_ + pos++] = base8 + j;
    }
}

// ---------------------------------------------------------------------------
// K5: mask dense enc in place; zero-words write zeros WITHOUT reading enc
// ---------------------------------------------------------------------------
__global__ void apply_mask(float* __restrict__ enc, const unsigned* __restrict__ bmask)
{
    size_t idx = ((size_t)blockIdx.x * blockDim.x + threadIdx.x) * 4;
    size_t m = idx >> 12;             // / D_
    int d = (int)(idx & (D_ - 1));
    int b = (int)(m / T_);
    int t = (int)(m % T_);
    int wrow = b * NW_ + (t >> 3);
    unsigned word = bmask[(size_t)wrow * (D_ / 32) + (d >> 5)];
    unsigned nib = (word >> (d & 31)) & 0xFu;   // idx is 4-aligned in d
    float4 v = {0.f, 0.f, 0.f, 0.f};
    if (nib) {
        v = *(float4*)(enc + idx);
        if (!(nib & 1u)) v.x = 0.f;
        if (!(nib & 2u)) v.y = 0.f;
        if (!(nib & 4u)) v.z = 0.f;
        if (!(nib & 8u)) v.w = 0.f;
    }
    *(float4*)(enc + idx) = v;
}

// ---------------------------------------------------------------------------
// K6: sparse decode per window; K-loop 2x unrolled for load ILP
// (accumulation order preserved exactly: i then i+1)
// ---------------------------------------------------------------------------
__global__ __launch_bounds__(256) void decode_win(
    const float* __restrict__ enc,
    const int* __restrict__ idxlist,
    const float* __restrict__ WdT,    // (D_, C_)
    const float* __restrict__ b_dec,
    float* __restrict__ recon)        // (M_, C_)
{
    int row = blockIdx.x;
    int b = row / NW_, w = row % NW_;
    int t0 = b * T_ + w * WIN_;
    __shared__ int sidx[K_];
    __shared__ float act[K_][12];
    int tid = threadIdx.x;
    if (tid < K_) sidx[tid] = idxlist[(size_t)row * K_ + tid];
    __syncthreads();
    {
        int ci = tid >> 1;
        int j4 = (tid & 1) * 4;
        int dd = sidx[ci];
        #pragma unroll
        for (int j = 0; j < 4; j++)
            act[ci][j4 + j] = enc[(size_t)(t0 + j4 + j) * D_ + dd];
    }
    __syncthreads();

    float accv[WIN_][4] = {};
    int c0 = tid * 4;
    for (int i = 0; i < K_; i += 2) {
        int d0v = sidx[i], d1v = sidx[i + 1];
        float4 wv0 = *(const float4*)(WdT + (size_t)d0v * C_ + c0);
        float4 wv1 = *(const float4*)(WdT + (size_t)d1v * C_ + c0);
        float4 a03_0 = *(const float4*)(&act[i][0]);
        float4 a47_0 = *(const float4*)(&act[i][4]);
        float4 a03_1 = *(const float4*)(&act[i + 1][0]);
        float4 a47_1 = *(const float4*)(&act[i + 1][4]);
        float aj0[8] = {a03_0.x, a03_0.y, a03_0.z, a03_0.w, a47_0.x, a47_0.y, a47_0.z, a47_0.w};
        float aj1[8] = {a03_1.x, a03_1.y, a03_1.z, a03_1.w, a47_1.x, a47_1.y, a47_1.z, a47_1.w};
        #pragma unroll
        for (int j = 0; j < WIN_; j++) {
            accv[j][0] = fmaf(aj0[j], wv0.x, accv[j][0]);
            accv[j][1] = fmaf(aj0[j], wv0.y, accv[j][1]);
            accv[j][2] = fmaf(aj0[j], wv0.z, accv[j][2]);
            accv[j][3] = fmaf(aj0[j], wv0.w, accv[j][3]);
        }
        #pragma unroll
        for (int j = 0; j < WIN_; j++) {
            accv[j][0] = fmaf(aj1[j], wv1.x, accv[j][0]);
            accv[j][1] = fmaf(aj1[j], wv1.y, accv[j][1]);
            accv[j][2] = fmaf(aj1[j], wv1.z, accv[j][2]);
            accv[j][3] = fmaf(aj1[j], wv1.w, accv[j][3]);
        }
    }
    float4 bd = *(const float4*)(b_dec + c0);
    #pragma unroll
    for (int j = 0; j < WIN_; j++) {
        float4 o;
        o.x = accv[j][0] + bd.x; o.y = accv[j][1] + bd.y;
        o.z = accv[j][2] + bd.z; o.w = accv[j][3] + bd.w;
        *(float4*)(recon + (size_t)(t0 + j) * C_ + c0) = o;
    }
}

// ---------------------------------------------------------------------------
extern "C" void kernel_launch(void* const* d_in, const int* in_sizes, int n_in,
                              void* d_out, int out_size, void* d_ws, size_t ws_size,
                              hipStream_t stream)
{
    const float* x     = (const float*)d_in[0];
    const float* W_enc = (const float*)d_in[1];
    const float* b_enc = (const float*)d_in[2];
    const float* W_dec = (const float*)d_in[3];
    const float* b_dec = (const float*)d_in[4];

    float* out   = (float*)d_out;
    float* recon = out;                        // M_*C_ floats
    float* enc   = out + (size_t)M_ * C_;      // M_*D_ floats (dense -> masked)

    // scratch inside recon region (dead before decode writes recon)
    unsigned short* xbf   = (unsigned short*)recon;                       // 16.8 MB
    float*          wsums = (float*)((char*)recon + (size_t)M_ * C_ * 2); // 16.8 MB

    // persistent scratch in d_ws
    char* ws = (char*)d_ws;
    float*          WdT     = (float*)ws;                                   // 16.8 MB
    unsigned*       bmask   = (unsigned*)(ws + (size_t)D_ * C_ * 4);        // 512 KB
    int*            idxlist = (int*)((char*)bmask + (size_t)(B_ * NW_) * (D_ / 32) * 4);
    float*          benc2   = (float*)((char*)idxlist + (size_t)(B_ * NW_) * K_ * 4);
    unsigned short* wencbf  = (unsigned short*)((char*)benc2 + D_ * 4);     // 8.4 MB

    prep_cvt_wenc<<<D_, 256, 0, stream>>>(W_enc, b_enc, b_dec, wencbf, benc2);
    cvt_bf16<<<(M_ * C_ / 8 + 255) / 256, 256, 0, stream>>>(x, xbf, M_ * C_ / 8);
    transpose_wdec<<<dim3(D_ / 32, C_ / 32), dim3(32, 8), 0, stream>>>(W_dec, WdT);
    mfma_gemm_dense<<<dim3(32, 64), 256, 0, stream>>>(xbf, wencbf, benc2, enc, wsums);
    fixup_topk<<<B_ * NW_, FT_NT, 0, stream>>>(wsums, x, W_enc, benc2, bmask, idxlist);
    apply_mask<<<(int)((size_t)M_ * D_ / 4 / 256), 256, 0, stream>>>(enc, bmask);
    decode_win<<<B_ * NW_, 256, 0, stream>>>(enc, idxlist, WdT, b_dec, recon);
}

// Round 12
// 275.393 us; speedup vs baseline: 1.0720x; 1.0720x over previous
//
#include <hip/hip_runtime.h>

#define B_   16
#define T_   512
#define C_   1024
#define D_   4096
#define K_   128
#define WIN_ 8
#define NW_  (T_ / WIN_)   // 64
#define M_   (B_ * T_)     // 8192

typedef __attribute__((ext_vector_type(8))) short bf16x8_t;
typedef __attribute__((ext_vector_type(4))) float f32x4_t;

__device__ __forceinline__ void gload16(const void* g, void* l) {
    __builtin_amdgcn_global_load_lds(
        (const __attribute__((address_space(1))) void*)g,
        (__attribute__((address_space(3))) void*)l, 16, 0, 0);
}

__device__ __forceinline__ unsigned short f2bf(float f) {
    unsigned u = __float_as_uint(f);
    unsigned r = (u + 0x7fffu + ((u >> 16) & 1u)) >> 16;
    return (unsigned short)r;
}
__device__ __forceinline__ float bf2f(unsigned short h) {
    return __uint_as_float((unsigned)h << 16);
}

__device__ __forceinline__ unsigned f2key(float f) {
    unsigned u = __float_as_uint(f);
    return (u & 0x80000000u) ? ~u : (u | 0x80000000u);
}
__device__ __forceinline__ float key2f(unsigned k) {
    unsigned u = (k & 0x80000000u) ? (k & 0x7fffffffu) : ~k;
    return __uint_as_float(u);
}

// ---------------------------------------------------------------------------
// K0 (fused): wencbf = bf16(W_enc)  AND  benc2[d] = b_enc[d] - W_enc[d,:].b_dec
// ---------------------------------------------------------------------------
__global__ __launch_bounds__(256) void prep_cvt_wenc(
    const float* __restrict__ W_enc, const float* __restrict__ b_enc,
    const float* __restrict__ b_dec, unsigned short* __restrict__ wencbf,
    float* __restrict__ benc2)
{
    int d = blockIdx.x;
    int tid = threadIdx.x;
    float4 wv = ((const float4*)(W_enc + (size_t)d * C_))[tid];
    uint2 o;
    o.x = (unsigned)f2bf(wv.x) | ((unsigned)f2bf(wv.y) << 16);
    o.y = (unsigned)f2bf(wv.z) | ((unsigned)f2bf(wv.w) << 16);
    ((uint2*)(wencbf + (size_t)d * C_))[tid] = o;
    float4 bv = ((const float4*)b_dec)[tid];
    float s = wv.x * bv.x + wv.y * bv.y + wv.z * bv.z + wv.w * bv.w;
    __shared__ float red[256];
    red[tid] = s;
    __syncthreads();
    for (int off = 128; off > 0; off >>= 1) {
        if (tid < off) red[tid] += red[tid + off];
        __syncthreads();
    }
    if (tid == 0) benc2[d] = b_enc[d] - red[0];
}

// ---------------------------------------------------------------------------
// K1: fp32 -> bf16 (8 elems/thread) for x
// ---------------------------------------------------------------------------
__global__ void cvt_bf16(const float* __restrict__ in, unsigned short* __restrict__ out, int n8)
{
    int i = blockIdx.x * blockDim.x + threadIdx.x;
    if (i >= n8) return;
    const float4* p = (const float4*)(in + (size_t)i * 8);
    float4 a = p[0], b = p[1];
    uint4 o;
    o.x = (unsigned)f2bf(a.x) | ((unsigned)f2bf(a.y) << 16);
    o.y = (unsigned)f2bf(a.z) | ((unsigned)f2bf(a.w) << 16);
    o.z = (unsigned)f2bf(b.x) | ((unsigned)f2bf(b.y) << 16);
    o.w = (unsigned)f2bf(b.z) | ((unsigned)f2bf(b.w) << 16);
    ((uint4*)out)[i] = o;
}

// ---------------------------------------------------------------------------
// K2: transpose W_dec (C,D) -> WdTb (D,C) in bf16 (halves decode L3 traffic)
// ---------------------------------------------------------------------------
__global__ void transpose_wdec(const float* __restrict__ W, unsigned short* __restrict__ WT)
{
    __shared__ float tile[32][33];
    int d0 = blockIdx.x * 32;
    int c0 = blockIdx.y * 32;
    int tx = threadIdx.x, ty = threadIdx.y;  // (32,8)
    #pragma unroll
    for (int i = 0; i < 32; i += 8)
        tile[ty + i][tx] = W[(size_t)(c0 + ty + i) * D_ + d0 + tx];
    __syncthreads();
    #pragma unroll
    for (int i = 0; i < 32; i += 8)
        WT[(size_t)(d0 + ty + i) * C_ + c0 + tx] = f2bf(tile[tx][ty + i]);
}

// ---------------------------------------------------------------------------
// K3: bf16 MFMA GEMM — round-4/7/9/10 proven kernel, verbatim.
// ---------------------------------------------------------------------------
__global__ __launch_bounds__(256) void mfma_gemm_dense(
    const unsigned short* __restrict__ Abf,  // x bf16 (M_, C_)
    const unsigned short* __restrict__ Bbf,  // W_enc bf16 (D_, C_)
    const float* __restrict__ benc2,
    float* __restrict__ enc,                 // (M_, D_) dense activations
    float* __restrict__ wsums)               // (B_*NW_, D_)
{
    __shared__ unsigned short lA[128 * 32];
    __shared__ unsigned short lB[128 * 32];
    __shared__ float cst[4][16][68];         // wave-private C-stage (17 KB)
    int tid = threadIdx.x;
    int lane = tid & 63;
    int wv = tid >> 6;
    int wm = wv >> 1, wn = wv & 1;

    int lid = blockIdx.y * gridDim.x + blockIdx.x;
    int sw = (lid & 7) * 256 + (lid >> 3);
    int bn = sw & 31, bm = sw >> 5;

    f32x4_t acc[4][4];
    #pragma unroll
    for (int i = 0; i < 4; i++)
        #pragma unroll
        for (int j = 0; j < 4; j++) acc[i][j] = (f32x4_t){0.f, 0.f, 0.f, 0.f};

    const unsigned short* Ab = Abf + (size_t)bm * 128 * C_;
    const unsigned short* Bb = Bbf + (size_t)bn * 128 * C_;

    int m_s[2], u_s[2];
    #pragma unroll
    for (int q = 0; q < 2; q++) {
        int p = q * 256 + tid;
        int m = p >> 2, v = p & 3;
        m_s[q] = m;
        u_s[q] = v ^ ((m >> 1) & 3);
    }

    int r = lane & 15, g = lane >> 4;
    for (int k0 = 0; k0 < C_; k0 += 32) {
        __syncthreads();
        #pragma unroll
        for (int q = 0; q < 2; q++) {
            gload16(Ab + (size_t)m_s[q] * C_ + k0 + u_s[q] * 8,
                    &lA[(q * 256 + wv * 64) * 8]);
            gload16(Bb + (size_t)m_s[q] * C_ + k0 + u_s[q] * 8,
                    &lB[(q * 256 + wv * 64) * 8]);
        }
        __syncthreads();
        bf16x8_t af[4], bfr[4];
        #pragma unroll
        for (int mi = 0; mi < 4; mi++) {
            int m = wm * 64 + mi * 16 + r;
            int u = g ^ ((m >> 1) & 3);
            af[mi] = *(const bf16x8_t*)&lA[m * 32 + u * 8];
        }
        #pragma unroll
        for (int ni = 0; ni < 4; ni++) {
            int d = wn * 64 + ni * 16 + r;
            int u = g ^ ((d >> 1) & 3);
            bfr[ni] = *(const bf16x8_t*)&lB[d * 32 + u * 8];
        }
        #pragma unroll
        for (int mi = 0; mi < 4; mi++)
            #pragma unroll
            for (int ni = 0; ni < 4; ni++)
                acc[mi][ni] = __builtin_amdgcn_mfma_f32_16x16x32_bf16(
                    af[mi], bfr[ni], acc[mi][ni], 0, 0, 0);
    }

    int b = bm >> 2;
    int t_blk = (bm & 3) * 128;
    int dbase = bn * 128 + wn * 64;
    int mbase_w = bm * 128 + wm * 64;
    int wbase = b * NW_ + (t_blk >> 3) + wm * 8;

    float bias_r[4];
    #pragma unroll
    for (int ni = 0; ni < 4; ni++) bias_r[ni] = benc2[dbase + ni * 16 + r];

    float wsv[4][4];
    #pragma unroll
    for (int mi = 0; mi < 4; mi++) {
        #pragma unroll
        for (int ni = 0; ni < 4; ni++) {
            float s = 0.f;
            #pragma unroll
            for (int q = 0; q < 4; q++) {
                float v = acc[mi][ni][q] + bias_r[ni];
                v = v > 0.f ? v : 0.f;
                cst[wv][g * 4 + q][ni * 16 + r] = v;
                s += v;
            }
            float partner = __shfl_xor(s, 16);
            wsv[mi][ni] = s + partner;
        }
        #pragma unroll
        for (int ri = 0; ri < 4; ri++) {
            int row = ri * 4 + (lane >> 4);
            int c4 = (lane & 15) * 4;
            float4 vv = *(const float4*)&cst[wv][row][c4];
            *(float4*)(enc + (size_t)(mbase_w + mi * 16 + row) * D_ + dbase + c4) = vv;
        }
    }

    if ((g & 1) == 0) {
        #pragma unroll
        for (int mi = 0; mi < 4; mi++)
            #pragma unroll
            for (int ni = 0; ni < 4; ni++)
                cst[wv][mi * 2 + (g >> 1)][ni * 16 + r] = wsv[mi][ni];
    }
    #pragma unroll
    for (int it = 0; it < 2; it++) {
        int row = lane >> 3;
        int c4 = (lane & 7) * 4 + it * 32;
        float4 vv = *(const float4*)&cst[wv][row][c4];
        *(float4*)(wsums + (size_t)(wbase + row) * D_ + dbase + c4) = vv;
    }
}

// ---------------------------------------------------------------------------
// Selection helpers (round-9/10 proven)
// ---------------------------------------------------------------------------
__device__ __forceinline__ void find_bucket(
    const int* hist, int need, int shift, unsigned pref,
    unsigned* shp, int* shn, int tid)
{
    if (tid < 64) {
        int L = tid;
        int h0 = hist[L * 4], h1 = hist[L * 4 + 1];
        int h2 = hist[L * 4 + 2], h3 = hist[L * 4 + 3];
        int s3 = h3, s2 = h2 + s3, s1 = h1 + s2, s0 = h0 + s1;
        int T = s0, I = T;
        #pragma unroll
        for (int off = 1; off < 64; off <<= 1) {
            int t = __shfl_down(I, off);
            if (L + off < 64) I += t;
        }
        int H = I - T;   // suffix sum of buckets in higher lanes
        int S[5] = {H + s0, H + s1, H + s2, H + s3, H};
        #pragma unroll
        for (int j = 0; j < 4; j++) {
            if (S[j] >= need && S[j + 1] < need) {
                *shp = pref | ((unsigned)(L * 4 + j) << shift);
                *shn = need - S[j + 1];
            }
        }
    }
    __syncthreads();
}

__device__ __forceinline__ void radix_select(
    const unsigned* keys, int n, int need0, int npass, unsigned maxkey,
    int* hist, unsigned* shp, int* shn, int tid)
{
    if (tid == 0) { *shp = 0u; *shn = need0; }
    __syncthreads();
    for (int pass = 0; pass < npass; ++pass) {
        int shift = 24 - pass * 8;
        unsigned pref = *shp;
        int need = *shn;
        unsigned pmask = (pass == 0) ? 0u : (0xFFFFFFFFu << (shift + 8));
        hist[tid] = 0;
        __syncthreads();
        for (int i = tid; i < n; i += 256) {
            unsigned k = keys[i];
            if (k <= maxkey && (k & pmask) == pref)
                atomicAdd(&hist[(k >> shift) & 0xFF], 1);
        }
        __syncthreads();
        find_bucket(hist, need, shift, pref, shp, shn, tid);
    }
}

__device__ __forceinline__ int block_prefix_excl(int v, int* wsum, int tid)
{
    __syncthreads();                 // protect wsum reuse
    int lane = tid & 63, wv = tid >> 6;
    int x = v;
    #pragma unroll
    for (int off = 1; off < 64; off <<= 1) {
        int t = __shfl_up(x, off);
        if (lane >= off) x += t;
    }
    if (lane == 63) wsum[wv] = x;
    __syncthreads();
    int base = 0;
    #pragma unroll
    for (int w2 = 0; w2 < 3; w2++) if (w2 < wv) base += wsum[w2];
    return base + x - v;
}

// ---------------------------------------------------------------------------
// K4 (fused): round-10 version verbatim (256 threads — 512-thread variant
// regressed: barrier cost up, per-thread work down to 8 items/phase).
// ---------------------------------------------------------------------------
#define DELTA 0.15f
#define MAXCAND 320

__global__ __launch_bounds__(256) void fixup_topk(
    const float* __restrict__ wsums, const float* __restrict__ x,
    const float* __restrict__ W_enc, const float* __restrict__ benc2,
    unsigned* __restrict__ bmask, int* __restrict__ idxlist)
{
    int row = blockIdx.x;             // b*NW + w
    int b = row / NW_, w = row % NW_;
    int t0g = b * T_ + w * WIN_;
    __shared__ unsigned keys[D_];     // 16 KB (mixed approx/exact keys)
    __shared__ float xs[WIN_][C_];    // 32 KB (whist overlay during P1)
    __shared__ int hist[256];         // 1 KB (hbits overlay in P4)
    __shared__ int wsum[4];
    __shared__ unsigned sh_prefix;
    __shared__ int sh_need;
    __shared__ int cand[MAXCAND];
    __shared__ unsigned ckeys[MAXCAND];
    __shared__ int sh_ncand, sh_nhi;
    unsigned short* hbits = (unsigned short*)hist;   // used only in P4
    int* whist = (int*)xs;                           // [4][256], pass-0 only
    int tid = threadIdx.x;

    for (int i = tid; i < D_ / 4; i += 256) {
        float4 v = ((const float4*)(wsums + (size_t)row * D_))[i];
        keys[i * 4 + 0] = f2key(v.x);
        keys[i * 4 + 1] = f2key(v.y);
        keys[i * 4 + 2] = f2key(v.z);
        keys[i * 4 + 3] = f2key(v.w);
    }
    for (int i = tid; i < 1024; i += 256) whist[i] = 0;
    if (tid == 0) { sh_ncand = 0; sh_nhi = 0; }
    __syncthreads();

    // ---- P1 pass 0: per-wave histograms ----
    {
        int* myh = whist + (tid >> 6) * 256;
        for (int i = tid; i < D_; i += 256)
            atomicAdd(&myh[keys[i] >> 24], 1);
        __syncthreads();
        hist[tid] = whist[tid] + whist[256 + tid] + whist[512 + tid] + whist[768 + tid];
        __syncthreads();
        find_bucket(hist, K_, 24, 0u, &sh_prefix, &sh_need, tid);
    }
    // ---- P1 passes 1..2 (24-bit prefix suffices) ----
    for (int pass = 1; pass < 3; ++pass) {
        int shift = 24 - pass * 8;
        unsigned pref = sh_prefix;
        int need = sh_need;
        unsigned pmask = 0xFFFFFFFFu << (shift + 8);
        hist[tid] = 0;
        __syncthreads();
        for (int i = tid; i < D_; i += 256) {
            unsigned k = keys[i];
            if ((k & pmask) == pref)
                atomicAdd(&hist[(k >> shift) & 0xFF], 1);
        }
        __syncthreads();
        find_bucket(hist, need, shift, pref, &sh_prefix, &sh_need, tid);
    }
    float kthf = key2f(sh_prefix);
    unsigned TH_HI = f2key(kthf + DELTA);
    unsigned TH_LO = f2key(kthf - DELTA);

    // ---- load xs (whist region dead now) + collect candidates ----
    for (int i = tid; i < WIN_ * C_ / 4; i += 256)
        ((float4*)xs)[i] = ((const float4*)(x + (size_t)t0g * C_))[i];
    {
        int myhi = 0;
        for (int i = tid; i < D_; i += 256) {
            unsigned k = keys[i];
            if (k > TH_HI) myhi++;
            else if (k >= TH_LO) {
                int pos = atomicAdd(&sh_ncand, 1);
                if (pos < MAXCAND) cand[pos] = i;
            }
        }
        if (myhi) atomicAdd(&sh_nhi, myhi);
    }
    __syncthreads();
    int nc = sh_ncand < MAXCAND ? sh_ncand : MAXCAND;

    // ---- P2: exact fp32 recompute (one candidate per wave) ----
    {
        int wvi = tid >> 6, ln = tid & 63;
        int c0 = ln * 4;
        for (int cb = wvi; cb < nc; cb += 4) {
            int d = cand[cb];
            const float* wrow = W_enc + (size_t)d * C_;
            float a[WIN_] = {0.f, 0.f, 0.f, 0.f, 0.f, 0.f, 0.f, 0.f};
            #pragma unroll
            for (int q = 0; q < 4; q++) {
                float4 wq = *(const float4*)(wrow + q * 256 + c0);
                #pragma unroll
                for (int j = 0; j < WIN_; j++) {
                    float4 xq = *(const float4*)(&xs[j][q * 256 + c0]);
                    a[j] = fmaf(wq.x, xq.x, a[j]);
                    a[j] = fmaf(wq.y, xq.y, a[j]);
                    a[j] = fmaf(wq.z, xq.z, a[j]);
                    a[j] = fmaf(wq.w, xq.w, a[j]);
                }
            }
            #pragma unroll
            for (int off = 1; off < 64; off <<= 1)
                #pragma unroll
                for (int j = 0; j < WIN_; j++) a[j] += __shfl_xor(a[j], off);
            if (ln == 0) {
                float bias = benc2[d], s = 0.f;
                #pragma unroll
                for (int j = 0; j < WIN_; j++) {
                    float v = a[j] + bias;
                    s += v > 0.f ? v : 0.f;
                }
                unsigned k1 = f2key(s);
                keys[d] = k1;
                ckeys[cb] = k1;
            }
        }
    }
    __syncthreads();

    // ---- P3: finish n_hi; exact select among candidates (or fallback) ----
    for (int i = tid; i < nc; i += 256)
        if (ckeys[i] > TH_HI) atomicAdd(&sh_nhi, 1);
    __syncthreads();
    int need0 = K_ - sh_nhi;
    if (need0 > 0)
        radix_select(ckeys, nc, need0, 4, TH_HI, hist, &sh_prefix, &sh_need, tid);
    else
        radix_select(keys, D_, K_, 4, 0xFFFFFFFFu, hist, &sh_prefix, &sh_need, tid);
    unsigned kth = sh_prefix;
    int need_eq = sh_need;

    // ---- P4: emit bmask + ascending idxlist (tie-break lowest index) ----
    int base16 = tid * 16;
    unsigned mybits = 0;
    int eqcnt = 0;
    #pragma unroll
    for (int j = 0; j < 16; ++j) {
        unsigned k = keys[base16 + j];
        if (k > kth) mybits |= (1u << j);
        else if (k == kth) eqcnt++;
    }
    int rr = block_prefix_excl(eqcnt, wsum, tid);
    #pragma unroll
    for (int j = 0; j < 16; ++j) {
        unsigned k = keys[base16 + j];
        if (k == kth) { if (rr < need_eq) mybits |= (1u << j); rr++; }
    }
    hbits[tid] = (unsigned short)mybits;     // hist dead from here on
    __syncthreads();
    if (tid < D_ / 32)
        bmask[(size_t)row * (D_ / 32) + tid] =
            (unsigned)hbits[2 * tid] | ((unsigned)hbits[2 * tid + 1] << 16);

    int pos = block_prefix_excl(__popc(mybits), wsum, tid);
    #pragma unroll
    for (int j = 0; j < 16; ++j) {
        if (mybits & (1u << j)) idxlist[(size_t)row * K_ + pos++] = base16 + j;
    }
}

// ---------------------------------------------------------------------------
// K5: mask dense enc in place; zero-words write zeros WITHOUT reading enc
// ---------------------------------------------------------------------------
__global__ void apply_mask(float* __restrict__ enc, const unsigned* __restrict__ bmask)
{
    size_t idx = ((size_t)blockIdx.x * blockDim.x + threadIdx.x) * 4;
    size_t m = idx >> 12;             // / D_
    int d = (int)(idx & (D_ - 1));
    int b = (int)(m / T_);
    int t = (int)(m % T_);
    int wrow = b * NW_ + (t >> 3);
    unsigned word = bmask[(size_t)wrow * (D_ / 32) + (d >> 5)];
    unsigned nib = (word >> (d & 31)) & 0xFu;   // idx is 4-aligned in d
    float4 v = {0.f, 0.f, 0.f, 0.f};
    if (nib) {
        v = *(float4*)(enc + idx);
        if (!(nib & 1u)) v.x = 0.f;
        if (!(nib & 2u)) v.y = 0.f;
        if (!(nib & 4u)) v.z = 0.f;
        if (!(nib & 8u)) v.w = 0.f;
    }
    *(float4*)(enc + idx) = v;
}

// ---------------------------------------------------------------------------
// K6: sparse decode per window, bf16 WdT (halves the dominant L3 traffic)
// ---------------------------------------------------------------------------
__global__ __launch_bounds__(256) void decode_win(
    const float* __restrict__ enc,
    const int* __restrict__ idxlist,
    const unsigned short* __restrict__ WdTb,  // (D_, C_) bf16
    const float* __restrict__ b_dec,
    float* __restrict__ recon)                // (M_, C_)
{
    int row = blockIdx.x;
    int b = row / NW_, w = row % NW_;
    int t0 = b * T_ + w * WIN_;
    __shared__ int sidx[K_];
    __shared__ float act[K_][12];
    int tid = threadIdx.x;
    if (tid < K_) sidx[tid] = idxlist[(size_t)row * K_ + tid];
    __syncthreads();
    {
        int ci = tid >> 1;
        int j4 = (tid & 1) * 4;
        int dd = sidx[ci];
        #pragma unroll
        for (int j = 0; j < 4; j++)
            act[ci][j4 + j] = enc[(size_t)(t0 + j4 + j) * D_ + dd];
    }
    __syncthreads();

    float accv[WIN_][4] = {};
    int c0 = tid * 4;
    for (int i = 0; i < K_; ++i) {
        int d = sidx[i];
        ushort4 wu = *(const ushort4*)(WdTb + (size_t)d * C_ + c0);
        float4 wv = {bf2f(wu.x), bf2f(wu.y), bf2f(wu.z), bf2f(wu.w)};
        float4 a03 = *(const float4*)(&act[i][0]);
        float4 a47 = *(const float4*)(&act[i][4]);
        float aj[8] = {a03.x, a03.y, a03.z, a03.w, a47.x, a47.y, a47.z, a47.w};
        #pragma unroll
        for (int j = 0; j < WIN_; j++) {
            accv[j][0] = fmaf(aj[j], wv.x, accv[j][0]);
            accv[j][1] = fmaf(aj[j], wv.y, accv[j][1]);
            accv[j][2] = fmaf(aj[j], wv.z, accv[j][2]);
            accv[j][3] = fmaf(aj[j], wv.w, accv[j][3]);
        }
    }
    float4 bd = *(const float4*)(b_dec + c0);
    #pragma unroll
    for (int j = 0; j < WIN_; j++) {
        float4 o;
        o.x = accv[j][0] + bd.x; o.y = accv[j][1] + bd.y;
        o.z = accv[j][2] + bd.z; o.w = accv[j][3] + bd.w;
        *(float4*)(recon + (size_t)(t0 + j) * C_ + c0) = o;
    }
}

// ---------------------------------------------------------------------------
extern "C" void kernel_launch(void* const* d_in, const int* in_sizes, int n_in,
                              void* d_out, int out_size, void* d_ws, size_t ws_size,
                              hipStream_t stream)
{
    const float* x     = (const float*)d_in[0];
    const float* W_enc = (const float*)d_in[1];
    const float* b_enc = (const float*)d_in[2];
    const float* W_dec = (const float*)d_in[3];
    const float* b_dec = (const float*)d_in[4];

    float* out   = (float*)d_out;
    float* recon = out;                        // M_*C_ floats
    float* enc   = out + (size_t)M_ * C_;      // M_*D_ floats (dense -> masked)

    // scratch inside recon region (dead before decode writes recon)
    unsigned short* xbf   = (unsigned short*)recon;                       // 16.8 MB
    float*          wsums = (float*)((char*)recon + (size_t)M_ * C_ * 2); // 16.8 MB

    // persistent scratch in d_ws
    char* ws = (char*)d_ws;
    unsigned short* WdTb    = (unsigned short*)ws;                          // 8.4 MB (bf16)
    unsigned*       bmask   = (unsigned*)(ws + (size_t)D_ * C_ * 4);        // 512 KB
    int*            idxlist = (int*)((char*)bmask + (size_t)(B_ * NW_) * (D_ / 32) * 4);
    float*          benc2   = (float*)((char*)idxlist + (size_t)(B_ * NW_) * K_ * 4);
    unsigned short* wencbf  = (unsigned short*)((char*)benc2 + D_ * 4);     // 8.4 MB

    prep_cvt_wenc<<<D_, 256, 0, stream>>>(W_enc, b_enc, b_dec, wencbf, benc2);
    cvt_bf16<<<(M_ * C_ / 8 + 255) / 256, 256, 0, stream>>>(x, xbf, M_ * C_ / 8);
    transpose_wdec<<<dim3(D_ / 32, C_ / 32), dim3(32, 8), 0, stream>>>(W_dec, WdTb);
    mfma_gemm_dense<<<dim3(32, 64), 256, 0, stream>>>(xbf, wencbf, benc2, enc, wsums);
    fixup_topk<<<B_ * NW_, 256, 0, stream>>>(wsums, x, W_enc, benc2, bmask, idxlist);
    apply_mask<<<(int)((size_t)M_ * D_ / 4 / 256), 256, 0, stream>>>(enc, bmask);
    decode_win<<<B_ * NW_, 256, 0, stream>>>(enc, idxlist, WdTb, b_dec, recon);
}